// Round 4
// baseline (396.004 us; speedup 1.0000x reference)
//
#include <hip/hip_runtime.h>
#include <stdint.h>

#define B_ 4
#define T_ 2048
#define C_ 1024
#define H_ 16
#define HD 64

typedef __attribute__((ext_vector_type(8))) short bf16x8;
typedef __attribute__((ext_vector_type(4))) float v4f;
typedef __attribute__((ext_vector_type(4))) uint32_t v4u;

static __device__ __forceinline__ short f2bf(float f) {
    union { float f; uint32_t u; } v; v.f = f;
    uint32_t u = v.u;
    uint32_t r = (u + 0x7fffu + ((u >> 16) & 1u)) >> 16;
    return (short)(r & 0xffffu);
}
static __device__ __forceinline__ short f2bf_trunc(float f) {
    union { float f; uint32_t u; } v; v.f = f;
    return (short)(v.u >> 16);
}
// round-half-up bf16 pack of 2 fp32 -> 1 dword (lo short = x). 3 VALU ops.
static __device__ __forceinline__ uint32_t pack2(float x, float y) {
    uint32_t a = __float_as_uint(x) + 0x8000u;
    uint32_t b = __float_as_uint(y) + 0x8000u;
    return __builtin_amdgcn_perm(b, a, 0x07060302u);
}
static __device__ __forceinline__ void gload_lds16(const void* g, void* l) {
    __builtin_amdgcn_global_load_lds(
        (const __attribute__((address_space(1))) void*)g,
        (__attribute__((address_space(3))) void*)l, 16, 0, 0);
}

// Convert 4 weight matrices (1M fp32 each) to bf16. grid (512,4) x 256.
__global__ __launch_bounds__(256) void convw(
    const float* __restrict__ w0, const float* __restrict__ w1,
    const float* __restrict__ w2, const float* __restrict__ w3,
    short* __restrict__ out)
{
    const float* src = (blockIdx.y == 0) ? w0 : (blockIdx.y == 1) ? w1 :
                       (blockIdx.y == 2) ? w2 : w3;
    short* dst = out + (size_t)blockIdx.y * (C_ * C_);
    int id = blockIdx.x * 256 + threadIdx.x;
    const float* p = src + (size_t)id * 8;
    v4f a0 = *(const v4f*)p, a1 = *(const v4f*)(p + 4);
    v4u dv;
    dv[0] = pack2(a0[0], a0[1]); dv[1] = pack2(a0[2], a0[3]);
    dv[2] = pack2(a1[0], a1[1]); dv[3] = pack2(a1[2], a1[3]);
    *(v4u*)&dst[(size_t)id * 8] = dv;
}

// Fused Q/K/V projection. grid (64, 8, 3): z selects {xq,xk,xv}.
// Always: Xs <- x[tok0..][k] (fp32 convert-stage), Ws <- W_z[fea0..][k] (gll).
// z<2: D = x*W^T (m=token), scatter to (b,h,t,d) [*qscale for z=0].
// z=2: operand roles swapped -> D = W*x^T (m=feature), scatter to (b,h,d,t).
__global__ __launch_bounds__(256) void qkv_gemm(
    const float* __restrict__ xq, const float* __restrict__ xk,
    const float* __restrict__ xv, const short* __restrict__ Wbf,
    short* __restrict__ Qh, short* __restrict__ Kh, short* __restrict__ Vh)
{
    const int K = C_;
    __shared__ short Xs[128 * 32];
    __shared__ short Ws[128 * 32];
    const int t = threadIdx.x;
    const int w = t >> 6, l = t & 63, g = l >> 4, c = l & 15;
    const int wm = w & 1, wn = w >> 1;
    const int z = blockIdx.z;
    const float* xp = (z == 0) ? xq : (z == 1) ? xk : xv;
    const short* wp = Wbf + (size_t)z * (C_ * C_);
    const int tok0 = blockIdx.x * 128, fea0 = blockIdx.y * 128;
    const bool swapped = (z == 2);

    v4f acc[4][4];
#pragma unroll
    for (int i = 0; i < 4; ++i)
#pragma unroll
        for (int j = 0; j < 4; ++j) acc[i][j] = (v4f){0.f, 0.f, 0.f, 0.f};

    for (int k0 = 0; k0 < K; k0 += 32) {
        __syncthreads();
#pragma unroll
        for (int i = 0; i < 2; ++i) {      // W via gll
            int cb = w * 2 + i;
            const short* gp = wp + (size_t)(fea0 + cb * 16 + (l >> 2)) * K + k0 + (l & 3) * 8;
            gload_lds16(gp, &Ws[cb * 512]);
        }
#pragma unroll
        for (int i = 0; i < 2; ++i) {      // x fp32 convert-stage
            int id = i * 256 + t;
            const float* p = xp + (size_t)(tok0 + (id >> 2)) * K + k0 + (id & 3) * 8;
            v4f a0 = *(const v4f*)p, a1 = *(const v4f*)(p + 4);
            v4u dv;
            dv[0] = pack2(a0[0], a0[1]); dv[1] = pack2(a0[2], a0[3]);
            dv[2] = pack2(a1[0], a1[1]); dv[3] = pack2(a1[2], a1[3]);
            *(v4u*)&Xs[id * 8] = dv;
        }
        __syncthreads();
        const short* Fa = swapped ? Ws : Xs;
        const short* Fb = swapped ? Xs : Ws;
        bf16x8 fa[4], fb[4];
#pragma unroll
        for (int i = 0; i < 4; ++i)
            fa[i] = *(const bf16x8*)&Fa[(wm * 64 + i * 16 + c) * 32 + g * 8];
#pragma unroll
        for (int j = 0; j < 4; ++j)
            fb[j] = *(const bf16x8*)&Fb[(wn * 64 + j * 16 + c) * 32 + g * 8];
#pragma unroll
        for (int i = 0; i < 4; ++i)
#pragma unroll
            for (int j = 0; j < 4; ++j)
                acc[i][j] = __builtin_amdgcn_mfma_f32_16x16x32_bf16(fa[i], fb[j], acc[i][j], 0, 0, 0);
    }
    const float osc = (z == 0) ? 0.18033688011112042f : 1.0f;  // log2(e)/sqrt(64)
    short* o = (z == 0) ? Qh : (z == 1) ? Kh : Vh;
    const int am0 = swapped ? fea0 : tok0;   // m-dimension base of D
    const int an0 = swapped ? tok0 : fea0;
#pragma unroll
    for (int i = 0; i < 4; ++i)
#pragma unroll
        for (int j = 0; j < 4; ++j)
#pragma unroll
            for (int r = 0; r < 4; ++r) {
                int m = am0 + wm * 64 + i * 16 + g * 4 + r;
                int n = an0 + wn * 64 + j * 16 + c;
                float vv = acc[i][j][r];
                if (!swapped) {       // m = token, n = feature
                    int b = m >> 11, tt = m & (T_ - 1);
                    int h = n >> 6, d = n & 63;
                    o[((size_t)(b * H_ + h) * T_ + tt) * HD + d] = f2bf(vv * osc);
                } else {              // m = feature, n = token
                    int b = n >> 11, tt = n & (T_ - 1);
                    int h = m >> 6, d = m & 63;
                    o[((size_t)(b * H_ + h) * HD + d) * T_ + tt] = f2bf(vv);
                }
            }
}

// Final projection: out = Y @ Wo^T + bo, fp32 out. 64x128 tile, grid (128,8).
__global__ __launch_bounds__(256) void gemm_out(
    const short* __restrict__ A, const short* __restrict__ Bm,
    float* __restrict__ Out, const float* __restrict__ bias)
{
    const int K = C_;
    __shared__ short As[64 * 32];
    __shared__ short Bs[128 * 32];
    const int t = threadIdx.x;
    const int w = t >> 6, l = t & 63, g = l >> 4, c = l & 15;
    const int wm = w & 1, wn = w >> 1;
    const int m0 = blockIdx.x * 64, n0 = blockIdx.y * 128;

    v4f acc[2][4];
#pragma unroll
    for (int i = 0; i < 2; ++i)
#pragma unroll
        for (int j = 0; j < 4; ++j) acc[i][j] = (v4f){0.f, 0.f, 0.f, 0.f};

    for (int k0 = 0; k0 < K; k0 += 32) {
        __syncthreads();
        {   // A: 256 chunks, 1/thread
            const short* gp = A + (size_t)(m0 + (t >> 2)) * K + k0 + (t & 3) * 8;
            gload_lds16(gp, &As[(size_t)t * 8]);
        }
#pragma unroll
        for (int i = 0; i < 2; ++i) {   // B: 512 chunks, 2/thread
            int cb = w * 2 + i;
            const short* gp = Bm + (size_t)(n0 + cb * 16 + (l >> 2)) * K + k0 + (l & 3) * 8;
            gload_lds16(gp, &Bs[cb * 512]);
        }
        __syncthreads();
        bf16x8 fa[2], fb[4];
#pragma unroll
        for (int i = 0; i < 2; ++i)
            fa[i] = *(const bf16x8*)&As[(wm * 32 + i * 16 + c) * 32 + g * 8];
#pragma unroll
        for (int j = 0; j < 4; ++j)
            fb[j] = *(const bf16x8*)&Bs[(wn * 64 + j * 16 + c) * 32 + g * 8];
#pragma unroll
        for (int i = 0; i < 2; ++i)
#pragma unroll
            for (int j = 0; j < 4; ++j)
                acc[i][j] = __builtin_amdgcn_mfma_f32_16x16x32_bf16(fa[i], fb[j], acc[i][j], 0, 0, 0);
    }
#pragma unroll
    for (int i = 0; i < 2; ++i)
#pragma unroll
        for (int j = 0; j < 4; ++j)
#pragma unroll
            for (int r = 0; r < 4; ++r) {
                int m = m0 + wm * 32 + i * 16 + g * 4 + r;
                int n = n0 + wn * 64 + j * 16 + c;
                Out[(size_t)m * C_ + n] = acc[i][j][r] + bias[n];
            }
}

// Flash attention, causal, no-rescale softmax (Q pre-scaled by log2(e)/8).
// Block = (b,h,pair{p,31-p}); K/V tile staged ONCE per kb and applied to both
// q-tiles (tile0 only while kb<=p); kf/vf fragments shared across tiles.
__global__ __launch_bounds__(256) void attn_kernel(
    const short* __restrict__ Q, const short* __restrict__ Kp,
    const short* __restrict__ Vt, short* __restrict__ Y)
{
    __shared__ short Ks[2 * 64 * 32];    // [dim-half][key][32] via gll
    __shared__ short Vs[64 * 72];        // [d][key] pad 72
    __shared__ short Ps[2][4 * 16 * 72]; // per-tile, per-wave P
    const int t = threadIdx.x;
    const int w = t >> 6, l = t & 63, g = l >> 4, c = l & 15;
    const int p = blockIdx.x & 15;
    const size_t bh = blockIdx.x >> 4;
    const int qt0 = p, qt1 = 31 - p;

    bf16x8 ones;
#pragma unroll
    for (int i = 0; i < 8; ++i) ones[i] = (short)0x3F80;

    bf16x8 qf[2][2];
#pragma unroll
    for (int ti = 0; ti < 2; ++ti) {
        int qb = (ti ? qt1 : qt0) * 64;
        const short* qp = &Q[(bh * T_ + qb + w * 16 + c) * HD + g * 8];
        qf[ti][0] = *(const bf16x8*)qp;
        qf[ti][1] = *(const bf16x8*)(qp + 32);
    }

    v4f O[2][4], accl[2];
#pragma unroll
    for (int ti = 0; ti < 2; ++ti) {
        accl[ti] = (v4f){0.f, 0.f, 0.f, 0.f};
#pragma unroll
        for (int d = 0; d < 4; ++d) O[ti][d] = (v4f){0.f, 0.f, 0.f, 0.f};
    }

    for (int kb = 0; kb <= qt1; ++kb) {
        const int kbase = kb * 64;
        __syncthreads();
#pragma unroll
        for (int i = 0; i < 2; ++i) {    // K via gll
            int gi = w * 2 + i;
            int hk = gi >> 2, rb = gi & 3;
            const short* gp = &Kp[(bh * T_ + kbase + rb * 16 + (l >> 2)) * HD + hk * 32 + (l & 3) * 8];
            gload_lds16(gp, &Ks[hk * 2048 + rb * 512]);
        }
#pragma unroll
        for (int i = 0; i < 2; ++i) {    // V (transposed layout)
            int id = i * 256 + t;
            int rr = id >> 3, cc = id & 7;
            *(bf16x8*)&Vs[rr * 72 + cc * 8] =
                *(const bf16x8*)&Vt[(bh * HD + rr) * T_ + kbase + cc * 8];
        }
        __syncthreads();

        const bool act0 = (kb <= qt0);
        float s2[2][4][4];
#pragma unroll
        for (int j = 0; j < 4; ++j) {    // kf shared by both tiles
            bf16x8 kf0 = *(const bf16x8*)&Ks[(j * 16 + c) * 32 + g * 8];
            bf16x8 kf1 = *(const bf16x8*)&Ks[2048 + (j * 16 + c) * 32 + g * 8];
            if (act0) {
                v4f sa = (v4f){0.f, 0.f, 0.f, 0.f};
                sa = __builtin_amdgcn_mfma_f32_16x16x32_bf16(qf[0][0], kf0, sa, 0, 0, 0);
                sa = __builtin_amdgcn_mfma_f32_16x16x32_bf16(qf[0][1], kf1, sa, 0, 0, 0);
#pragma unroll
                for (int r = 0; r < 4; ++r) s2[0][j][r] = sa[r];
            }
            v4f sb = (v4f){0.f, 0.f, 0.f, 0.f};
            sb = __builtin_amdgcn_mfma_f32_16x16x32_bf16(qf[1][0], kf0, sb, 0, 0, 0);
            sb = __builtin_amdgcn_mfma_f32_16x16x32_bf16(qf[1][1], kf1, sb, 0, 0, 0);
#pragma unroll
            for (int r = 0; r < 4; ++r) s2[1][j][r] = sb[r];
        }
        if (kb == qt0) {   // diagonal of tile0
#pragma unroll
            for (int j = 0; j < 4; ++j) {
                int key = kbase + j * 16 + c;
#pragma unroll
                for (int r = 0; r < 4; ++r)
                    if (key > qt0 * 64 + w * 16 + g * 4 + r) s2[0][j][r] = -3.0e38f;
            }
        }
        if (kb == qt1) {   // diagonal of tile1 (last kb)
#pragma unroll
            for (int j = 0; j < 4; ++j) {
                int key = kbase + j * 16 + c;
#pragma unroll
                for (int r = 0; r < 4; ++r)
                    if (key > qt1 * 64 + w * 16 + g * 4 + r) s2[1][j][r] = -3.0e38f;
            }
        }
        if (act0) {
#pragma unroll
            for (int r = 0; r < 4; ++r)
#pragma unroll
                for (int j = 0; j < 4; ++j)
                    Ps[0][w * 1152 + (g * 4 + r) * 72 + j * 16 + c] =
                        f2bf_trunc(__builtin_amdgcn_exp2f(s2[0][j][r]));
        }
#pragma unroll
        for (int r = 0; r < 4; ++r)
#pragma unroll
            for (int j = 0; j < 4; ++j)
                Ps[1][w * 1152 + (g * 4 + r) * 72 + j * 16 + c] =
                    f2bf_trunc(__builtin_amdgcn_exp2f(s2[1][j][r]));
        // PV: vf loaded once, feeds both tiles
#pragma unroll
        for (int s = 0; s < 2; ++s) {
            bf16x8 vf[4];
#pragma unroll
            for (int d = 0; d < 4; ++d)
                vf[d] = *(const bf16x8*)&Vs[(d * 16 + c) * 72 + s * 32 + g * 8];
            if (act0) {
                bf16x8 af = *(const bf16x8*)&Ps[0][w * 1152 + c * 72 + s * 32 + g * 8];
#pragma unroll
                for (int d = 0; d < 4; ++d)
                    O[0][d] = __builtin_amdgcn_mfma_f32_16x16x32_bf16(af, vf[d], O[0][d], 0, 0, 0);
                accl[0] = __builtin_amdgcn_mfma_f32_16x16x32_bf16(af, ones, accl[0], 0, 0, 0);
            }
            {
                bf16x8 af = *(const bf16x8*)&Ps[1][w * 1152 + c * 72 + s * 32 + g * 8];
#pragma unroll
                for (int d = 0; d < 4; ++d)
                    O[1][d] = __builtin_amdgcn_mfma_f32_16x16x32_bf16(af, vf[d], O[1][d], 0, 0, 0);
                accl[1] = __builtin_amdgcn_mfma_f32_16x16x32_bf16(af, ones, accl[1], 0, 0, 0);
            }
        }
    }
#pragma unroll
    for (int ti = 0; ti < 2; ++ti) {
        int qb = (ti ? qt1 : qt0) * 64;
#pragma unroll
        for (int r = 0; r < 4; ++r) {
            float rl = 1.0f / accl[ti][r];
            size_t rowoff = ((size_t)(bh >> 4) * T_ + qb + w * 16 + g * 4 + r) * C_ + (bh & 15) * HD;
#pragma unroll
            for (int d = 0; d < 4; ++d)
                Y[rowoff + d * 16 + c] = f2bf(O[ti][d][r] * rl);
        }
    }
}

extern "C" void kernel_launch(void* const* d_in, const int* in_sizes, int n_in,
                              void* d_out, int out_size, void* d_ws, size_t ws_size,
                              hipStream_t stream) {
    const float* xq = (const float*)d_in[0];
    const float* xk = (const float*)d_in[1];
    const float* xv = (const float*)d_in[2];
    const float* Wq = (const float*)d_in[3];
    const float* Wk = (const float*)d_in[4];
    const float* Wv = (const float*)d_in[5];
    const float* Wo = (const float*)d_in[6];
    const float* bo = (const float*)d_in[7];

    const size_t NE = (size_t)B_ * H_ * T_ * HD;   // 8.4M elems
    const size_t WE = (size_t)C_ * C_;
    short* Qh  = (short*)d_ws;
    short* Kh  = Qh + NE;
    short* Vt  = Kh + NE;
    short* Y   = Vt + NE;
    short* Wbf = Y + NE;                           // total 72 MB

    dim3 blk(256);
    hipLaunchKernelGGL(convw, dim3(512, 4), blk, 0, stream, Wq, Wk, Wv, Wo, Wbf);
    hipLaunchKernelGGL(qkv_gemm, dim3(64, 8, 3), blk, 0, stream,
                       xq, xk, xv, (const short*)Wbf, Qh, Kh, Vt);
    hipLaunchKernelGGL(attn_kernel, dim3(B_ * H_ * (T_ / 128)), blk, 0, stream, Qh, Kh, Vt, Y);
    hipLaunchKernelGGL(gemm_out, dim3(128, 8), blk, 0, stream,
                       (const short*)Y, (const short*)(Wbf + 3 * WE), (float*)d_out, bo);
}

// Round 5
// 387.421 us; speedup vs baseline: 1.0222x; 1.0222x over previous
//
#include <hip/hip_runtime.h>
#include <stdint.h>

#define B_ 4
#define T_ 2048
#define C_ 1024
#define H_ 16
#define HD 64

typedef __attribute__((ext_vector_type(8))) short bf16x8;
typedef __attribute__((ext_vector_type(4))) float v4f;
typedef __attribute__((ext_vector_type(4))) uint32_t v4u;

static __device__ __forceinline__ short f2bf(float f) {
    union { float f; uint32_t u; } v; v.f = f;
    uint32_t u = v.u;
    uint32_t r = (u + 0x7fffu + ((u >> 16) & 1u)) >> 16;
    return (short)(r & 0xffffu);
}
static __device__ __forceinline__ short f2bf_trunc(float f) {
    union { float f; uint32_t u; } v; v.f = f;
    return (short)(v.u >> 16);
}
// round-half-up bf16 pack of 2 fp32 -> 1 dword (lo short = x). 3 VALU ops.
static __device__ __forceinline__ uint32_t pack2(float x, float y) {
    uint32_t a = __float_as_uint(x) + 0x8000u;
    uint32_t b = __float_as_uint(y) + 0x8000u;
    return __builtin_amdgcn_perm(b, a, 0x07060302u);
}
static __device__ __forceinline__ void gload_lds16(const void* g, void* l) {
    __builtin_amdgcn_global_load_lds(
        (const __attribute__((address_space(1))) void*)g,
        (__attribute__((address_space(3))) void*)l, 16, 0, 0);
}

// Convert 4 weight matrices (1M fp32 each) to bf16. grid (512,4) x 256.
__global__ __launch_bounds__(256) void convw(
    const float* __restrict__ w0, const float* __restrict__ w1,
    const float* __restrict__ w2, const float* __restrict__ w3,
    short* __restrict__ out)
{
    const float* src = (blockIdx.y == 0) ? w0 : (blockIdx.y == 1) ? w1 :
                       (blockIdx.y == 2) ? w2 : w3;
    short* dst = out + (size_t)blockIdx.y * (C_ * C_);
    int id = blockIdx.x * 256 + threadIdx.x;
    const float* p = src + (size_t)id * 8;
    v4f a0 = *(const v4f*)p, a1 = *(const v4f*)(p + 4);
    v4u dv;
    dv[0] = pack2(a0[0], a0[1]); dv[1] = pack2(a0[2], a0[3]);
    dv[2] = pack2(a1[0], a1[1]); dv[3] = pack2(a1[2], a1[3]);
    *(v4u*)&dst[(size_t)id * 8] = dv;
}

// ---- LDS swizzle for 64B rows (4 chunks of 16B): LDS chunk q holds global
// chunk q ^ ((row>>1)&3). gll staging: lane l (row=l>>2) fetches global chunk
// (l&3)^((l>>3)&3). Frag read of global chunk g at row r: LDS chunk g^((r>>1)&3).
// Makes every b128 half-wave access hit each bank-group exactly 4x (min). ----

// Fused Q/K/V projection. grid (64, 8, 3): z selects {xq,xk,xv}.
// Xs <- x (fp32 convert-stage, swizzled write), Ws <- W_z (gll, swizzled fetch).
// z<2: D = x*W^T (m=token) -> (b,h,t,d) [*qscale for z=0].
// z=2: roles swapped -> D = W*x^T (m=feature) -> (b,h,d,t).
__global__ __launch_bounds__(256) void qkv_gemm(
    const float* __restrict__ xq, const float* __restrict__ xk,
    const float* __restrict__ xv, const short* __restrict__ Wbf,
    short* __restrict__ Qh, short* __restrict__ Kh, short* __restrict__ Vh)
{
    const int K = C_;
    __shared__ short Xs[128 * 32];
    __shared__ short Ws[128 * 32];
    const int t = threadIdx.x;
    const int w = t >> 6, l = t & 63, g = l >> 4, c = l & 15;
    const int wm = w & 1, wn = w >> 1;
    const int z = blockIdx.z;
    const float* xp = (z == 0) ? xq : (z == 1) ? xk : xv;
    const short* wp = Wbf + (size_t)z * (C_ * C_);
    const int tok0 = blockIdx.x * 128, fea0 = blockIdx.y * 128;
    const bool swapped = (z == 2);
    const int fsw = ((l >> 1) & 3);          // frag-read swizzle term (c>>1)&3
    const int gsw = (l & 3) ^ ((l >> 3) & 3); // gll fetch chunk

    v4f acc[4][4];
#pragma unroll
    for (int i = 0; i < 4; ++i)
#pragma unroll
        for (int j = 0; j < 4; ++j) acc[i][j] = (v4f){0.f, 0.f, 0.f, 0.f};

    for (int k0 = 0; k0 < K; k0 += 32) {
        __syncthreads();
#pragma unroll
        for (int i = 0; i < 2; ++i) {      // W via gll (swizzled fetch)
            int cb = w * 2 + i;
            const short* gp = wp + (size_t)(fea0 + cb * 16 + (l >> 2)) * K + k0 + gsw * 8;
            gload_lds16(gp, &Ws[cb * 512]);
        }
#pragma unroll
        for (int i = 0; i < 2; ++i) {      // x fp32 convert-stage (swizzled write)
            int id = i * 256 + t;
            int row = id >> 2, sub = id & 3;
            const float* p = xp + (size_t)(tok0 + row) * K + k0 + sub * 8;
            v4f a0 = *(const v4f*)p, a1 = *(const v4f*)(p + 4);
            v4u dv;
            dv[0] = pack2(a0[0], a0[1]); dv[1] = pack2(a0[2], a0[3]);
            dv[2] = pack2(a1[0], a1[1]); dv[3] = pack2(a1[2], a1[3]);
            *(v4u*)&Xs[row * 32 + (sub ^ ((row >> 1) & 3)) * 8] = dv;
        }
        __syncthreads();
        const short* Fa = swapped ? Ws : Xs;
        const short* Fb = swapped ? Xs : Ws;
        bf16x8 fa[4], fb[4];
#pragma unroll
        for (int i = 0; i < 4; ++i)
            fa[i] = *(const bf16x8*)&Fa[(wm * 64 + i * 16 + c) * 32 + ((0 ^ fsw)) * 8 + 0];
        // note: need chunk g of row; g is the lane quad -> chunk = g ^ fsw
#pragma unroll
        for (int i = 0; i < 4; ++i)
            fa[i] = *(const bf16x8*)&Fa[(wm * 64 + i * 16 + c) * 32 + (g ^ fsw) * 8];
#pragma unroll
        for (int j = 0; j < 4; ++j)
            fb[j] = *(const bf16x8*)&Fb[(wn * 64 + j * 16 + c) * 32 + (g ^ fsw) * 8];
#pragma unroll
        for (int i = 0; i < 4; ++i)
#pragma unroll
            for (int j = 0; j < 4; ++j)
                acc[i][j] = __builtin_amdgcn_mfma_f32_16x16x32_bf16(fa[i], fb[j], acc[i][j], 0, 0, 0);
    }
    const float osc = (z == 0) ? 0.18033688011112042f : 1.0f;  // log2(e)/sqrt(64)
    short* o = (z == 0) ? Qh : (z == 1) ? Kh : Vh;
    const int am0 = swapped ? fea0 : tok0;
    const int an0 = swapped ? tok0 : fea0;
#pragma unroll
    for (int i = 0; i < 4; ++i)
#pragma unroll
        for (int j = 0; j < 4; ++j)
#pragma unroll
            for (int r = 0; r < 4; ++r) {
                int m = am0 + wm * 64 + i * 16 + g * 4 + r;
                int n = an0 + wn * 64 + j * 16 + c;
                float vv = acc[i][j][r];
                if (!swapped) {       // m = token, n = feature
                    int b = m >> 11, tt = m & (T_ - 1);
                    int h = n >> 6, d = n & 63;
                    o[((size_t)(b * H_ + h) * T_ + tt) * HD + d] = f2bf(vv * osc);
                } else {              // m = feature, n = token
                    int b = n >> 11, tt = n & (T_ - 1);
                    int h = m >> 6, d = m & 63;
                    o[((size_t)(b * H_ + h) * HD + d) * T_ + tt] = f2bf(vv);
                }
            }
}

// Final projection: out = Y @ Wo^T + bo, fp32. 128x128 tile, all-gll, swizzled.
__global__ __launch_bounds__(256) void gemm_out(
    const short* __restrict__ A, const short* __restrict__ Bm,
    float* __restrict__ Out, const float* __restrict__ bias)
{
    const int K = C_;
    __shared__ short As[128 * 32];
    __shared__ short Bs[128 * 32];
    const int t = threadIdx.x;
    const int w = t >> 6, l = t & 63, g = l >> 4, c = l & 15;
    const int wm = w & 1, wn = w >> 1;
    const int m0 = blockIdx.x * 128, n0 = blockIdx.y * 128;
    const int fsw = ((l >> 1) & 3);
    const int gsw = (l & 3) ^ ((l >> 3) & 3);

    v4f acc[4][4];
#pragma unroll
    for (int i = 0; i < 4; ++i)
#pragma unroll
        for (int j = 0; j < 4; ++j) acc[i][j] = (v4f){0.f, 0.f, 0.f, 0.f};

    for (int k0 = 0; k0 < K; k0 += 32) {
        __syncthreads();
#pragma unroll
        for (int i = 0; i < 2; ++i) {
            int cb = w * 2 + i;
            const short* gp = A + (size_t)(m0 + cb * 16 + (l >> 2)) * K + k0 + gsw * 8;
            gload_lds16(gp, &As[cb * 512]);
        }
#pragma unroll
        for (int i = 0; i < 2; ++i) {
            int cb = w * 2 + i;
            const short* gp = Bm + (size_t)(n0 + cb * 16 + (l >> 2)) * K + k0 + gsw * 8;
            gload_lds16(gp, &Bs[cb * 512]);
        }
        __syncthreads();
        bf16x8 fa[4], fb[4];
#pragma unroll
        for (int i = 0; i < 4; ++i)
            fa[i] = *(const bf16x8*)&As[(wm * 64 + i * 16 + c) * 32 + (g ^ fsw) * 8];
#pragma unroll
        for (int j = 0; j < 4; ++j)
            fb[j] = *(const bf16x8*)&Bs[(wn * 64 + j * 16 + c) * 32 + (g ^ fsw) * 8];
#pragma unroll
        for (int i = 0; i < 4; ++i)
#pragma unroll
            for (int j = 0; j < 4; ++j)
                acc[i][j] = __builtin_amdgcn_mfma_f32_16x16x32_bf16(fa[i], fb[j], acc[i][j], 0, 0, 0);
    }
#pragma unroll
    for (int i = 0; i < 4; ++i)
#pragma unroll
        for (int j = 0; j < 4; ++j)
#pragma unroll
            for (int r = 0; r < 4; ++r) {
                int m = m0 + wm * 64 + i * 16 + g * 4 + r;
                int n = n0 + wn * 64 + j * 16 + c;
                Out[(size_t)m * C_ + n] = acc[i][j][r] + bias[n];
            }
}

// Flash attention, causal, no-rescale softmax (Q pre-scaled by log2(e)/8).
// Block = (b,h,pair{p,31-p}); K/V staged once per kb, shared by both q-tiles.
// Ks: [half][key][32] swizzled (64B rows); Vs: [d][key] 128B rows, swizzle row&7.
__global__ __launch_bounds__(256) void attn_kernel(
    const short* __restrict__ Q, const short* __restrict__ Kp,
    const short* __restrict__ Vt, short* __restrict__ Y)
{
    __shared__ short Ks[2 * 64 * 32];
    __shared__ short Vs[64 * 64];
    __shared__ short Ps[2][4 * 16 * 72]; // padded 72: reads/writes conflict-free
    const int t = threadIdx.x;
    const int w = t >> 6, l = t & 63, g = l >> 4, c = l & 15;
    const int p = blockIdx.x & 15;
    const size_t bh = blockIdx.x >> 4;
    const int qt0 = p, qt1 = 31 - p;
    const int fsw = ((l >> 1) & 3);
    const int gsw = (l & 3) ^ ((l >> 3) & 3);
    const int vgsw = (l & 7) ^ (l >> 3);      // Vs gll fetch chunk (128B rows)
    const int vfsw = (c & 7);                 // Vs frag-read swizzle term

    bf16x8 ones;
#pragma unroll
    for (int i = 0; i < 8; ++i) ones[i] = (short)0x3F80;

    bf16x8 qf[2][2];
#pragma unroll
    for (int ti = 0; ti < 2; ++ti) {
        int qb = (ti ? qt1 : qt0) * 64;
        const short* qp = &Q[(bh * T_ + qb + w * 16 + c) * HD + g * 8];
        qf[ti][0] = *(const bf16x8*)qp;
        qf[ti][1] = *(const bf16x8*)(qp + 32);
    }

    v4f O[2][4], accl[2];
#pragma unroll
    for (int ti = 0; ti < 2; ++ti) {
        accl[ti] = (v4f){0.f, 0.f, 0.f, 0.f};
#pragma unroll
        for (int d = 0; d < 4; ++d) O[ti][d] = (v4f){0.f, 0.f, 0.f, 0.f};
    }

    for (int kb = 0; kb <= qt1; ++kb) {
        const int kbase = kb * 64;
        __syncthreads();
#pragma unroll
        for (int i = 0; i < 2; ++i) {    // K via gll, swizzled
            int gi = w * 2 + i;
            int hk = gi >> 2, rb = gi & 3;
            const short* gp = &Kp[(bh * T_ + kbase + rb * 16 + (l >> 2)) * HD + hk * 32 + gsw * 8];
            gload_lds16(gp, &Ks[hk * 2048 + rb * 512]);
        }
#pragma unroll
        for (int i = 0; i < 2; ++i) {    // V via gll, swizzled (128B rows)
            int rb = w * 2 + i;
            const short* gp = &Vt[(bh * HD + rb * 8 + (l >> 3)) * T_ + kbase + vgsw * 8];
            gload_lds16(gp, &Vs[rb * 512]);
        }
        __syncthreads();

        const bool act0 = (kb <= qt0);
        float s2[2][4][4];
#pragma unroll
        for (int j = 0; j < 4; ++j) {    // kf shared by both tiles
            bf16x8 kf0 = *(const bf16x8*)&Ks[(j * 16 + c) * 32 + (g ^ fsw) * 8];
            bf16x8 kf1 = *(const bf16x8*)&Ks[2048 + (j * 16 + c) * 32 + (g ^ fsw) * 8];
            if (act0) {
                v4f sa = (v4f){0.f, 0.f, 0.f, 0.f};
                sa = __builtin_amdgcn_mfma_f32_16x16x32_bf16(qf[0][0], kf0, sa, 0, 0, 0);
                sa = __builtin_amdgcn_mfma_f32_16x16x32_bf16(qf[0][1], kf1, sa, 0, 0, 0);
#pragma unroll
                for (int r = 0; r < 4; ++r) s2[0][j][r] = sa[r];
            }
            v4f sb = (v4f){0.f, 0.f, 0.f, 0.f};
            sb = __builtin_amdgcn_mfma_f32_16x16x32_bf16(qf[1][0], kf0, sb, 0, 0, 0);
            sb = __builtin_amdgcn_mfma_f32_16x16x32_bf16(qf[1][1], kf1, sb, 0, 0, 0);
#pragma unroll
            for (int r = 0; r < 4; ++r) s2[1][j][r] = sb[r];
        }
        if (kb == qt0) {
#pragma unroll
            for (int j = 0; j < 4; ++j) {
                int key = kbase + j * 16 + c;
#pragma unroll
                for (int r = 0; r < 4; ++r)
                    if (key > qt0 * 64 + w * 16 + g * 4 + r) s2[0][j][r] = -3.0e38f;
            }
        }
        if (kb == qt1) {
#pragma unroll
            for (int j = 0; j < 4; ++j) {
                int key = kbase + j * 16 + c;
#pragma unroll
                for (int r = 0; r < 4; ++r)
                    if (key > qt1 * 64 + w * 16 + g * 4 + r) s2[1][j][r] = -3.0e38f;
            }
        }
        if (act0) {
#pragma unroll
            for (int r = 0; r < 4; ++r)
#pragma unroll
                for (int j = 0; j < 4; ++j)
                    Ps[0][w * 1152 + (g * 4 + r) * 72 + j * 16 + c] =
                        f2bf_trunc(__builtin_amdgcn_exp2f(s2[0][j][r]));
        }
#pragma unroll
        for (int r = 0; r < 4; ++r)
#pragma unroll
            for (int j = 0; j < 4; ++j)
                Ps[1][w * 1152 + (g * 4 + r) * 72 + j * 16 + c] =
                    f2bf_trunc(__builtin_amdgcn_exp2f(s2[1][j][r]));
        // PV: vf loaded once, feeds both tiles
#pragma unroll
        for (int s = 0; s < 2; ++s) {
            bf16x8 vf[4];
#pragma unroll
            for (int d = 0; d < 4; ++d)
                vf[d] = *(const bf16x8*)&Vs[(d * 16 + c) * 64 + (((s * 4 + g) ^ vfsw)) * 8];
            if (act0) {
                bf16x8 af = *(const bf16x8*)&Ps[0][w * 1152 + c * 72 + s * 32 + g * 8];
#pragma unroll
                for (int d = 0; d < 4; ++d)
                    O[0][d] = __builtin_amdgcn_mfma_f32_16x16x32_bf16(af, vf[d], O[0][d], 0, 0, 0);
                accl[0] = __builtin_amdgcn_mfma_f32_16x16x32_bf16(af, ones, accl[0], 0, 0, 0);
            }
            {
                bf16x8 af = *(const bf16x8*)&Ps[1][w * 1152 + c * 72 + s * 32 + g * 8];
#pragma unroll
                for (int d = 0; d < 4; ++d)
                    O[1][d] = __builtin_amdgcn_mfma_f32_16x16x32_bf16(af, vf[d], O[1][d], 0, 0, 0);
                accl[1] = __builtin_amdgcn_mfma_f32_16x16x32_bf16(af, ones, accl[1], 0, 0, 0);
            }
        }
    }
#pragma unroll
    for (int ti = 0; ti < 2; ++ti) {
        int qb = (ti ? qt1 : qt0) * 64;
#pragma unroll
        for (int r = 0; r < 4; ++r) {
            float rl = 1.0f / accl[ti][r];
            size_t rowoff = ((size_t)(bh >> 4) * T_ + qb + w * 16 + g * 4 + r) * C_ + (bh & 15) * HD;
#pragma unroll
            for (int d = 0; d < 4; ++d)
                Y[rowoff + d * 16 + c] = f2bf(O[ti][d][r] * rl);
        }
    }
}

extern "C" void kernel_launch(void* const* d_in, const int* in_sizes, int n_in,
                              void* d_out, int out_size, void* d_ws, size_t ws_size,
                              hipStream_t stream) {
    const float* xq = (const float*)d_in[0];
    const float* xk = (const float*)d_in[1];
    const float* xv = (const float*)d_in[2];
    const float* Wq = (const float*)d_in[3];
    const float* Wk = (const float*)d_in[4];
    const float* Wv = (const float*)d_in[5];
    const float* Wo = (const float*)d_in[6];
    const float* bo = (const float*)d_in[7];

    const size_t NE = (size_t)B_ * H_ * T_ * HD;   // 8.4M elems
    const size_t WE = (size_t)C_ * C_;
    short* Qh  = (short*)d_ws;
    short* Kh  = Qh + NE;
    short* Vt  = Kh + NE;
    short* Y   = Vt + NE;
    short* Wbf = Y + NE;                           // total 72 MB

    dim3 blk(256);
    hipLaunchKernelGGL(convw, dim3(512, 4), blk, 0, stream, Wq, Wk, Wv, Wo, Wbf);
    hipLaunchKernelGGL(qkv_gemm, dim3(64, 8, 3), blk, 0, stream,
                       xq, xk, xv, (const short*)Wbf, Qh, Kh, Vt);
    hipLaunchKernelGGL(attn_kernel, dim3(B_ * H_ * (T_ / 128)), blk, 0, stream, Qh, Kh, Vt, Y);
    hipLaunchKernelGGL(gemm_out, dim3(64, 8), blk, 0, stream,
                       (const short*)Y, (const short*)(Wbf + 3 * WE), (float*)d_out, bo);
}